// Round 3
// baseline (279.867 us; speedup 1.0000x reference)
//
#include <hip/hip_runtime.h>
#include <hip/hip_bf16.h>
#include <stdint.h>

#define BB 4
#define TT 2048
#define DD 1024
#define HH 16
#define MTOK (BB*TT)
#define NQ 4096            // q|k|v|g concat width
#define TC 32              // scan chunk length
#define NC (TT/TC)         // 64 chunks
#define BH (BB*HH)         // 64
#define ROWT (16*NQ)       // elements per 16-row blocked stripe

typedef __bf16 bf16x8 __attribute__((ext_vector_type(8)));
typedef float f32x4 __attribute__((ext_vector_type(4)));

__device__ __forceinline__ uint16_t f2bf(float f){
  uint32_t u = __float_as_uint(f);
  u += 0x7fffu + ((u >> 16) & 1u);
  return (uint16_t)(u >> 16);
}
__device__ __forceinline__ float bf2f(uint32_t h){ return __uint_as_float(h << 16); }
__device__ __forceinline__ float sigm(float z){ return 1.f / (1.f + __expf(-z)); }

__device__ __forceinline__ void gll16(const uint16_t* src, uint16_t* dst){
  __builtin_amdgcn_global_load_lds(
      (const __attribute__((address_space(1))) void*)src,
      (__attribute__((address_space(3))) void*)dst, 16, 0, 0);
}
__device__ __forceinline__ void block_barrier(){
  asm volatile("" ::: "memory");
  __builtin_amdgcn_s_barrier();
  asm volatile("" ::: "memory");
}
// extract bf16 element e (static) from a uint4 (8 bf16)
__device__ __forceinline__ float bfel(const uint4& v, int e){
  uint32_t wrd = ((e>>1)==0) ? v.x : ((e>>1)==1) ? v.y : ((e>>1)==2) ? v.z : v.w;
  return bf2f((e&1) ? (wrd >> 16) : (wrd & 0xffffu));
}

// ---------------- f32 -> bf16 cast ----------------
__global__ void cvt_kernel(const float* __restrict__ in, uint16_t* __restrict__ out, int n4){
  int i = blockIdx.x * blockDim.x + threadIdx.x;
  if (i < n4){
    float4 v = ((const float4*)in)[i];
    ushort4 o;
    o.x = f2bf(v.x); o.y = f2bf(v.y); o.z = f2bf(v.z); o.w = f2bf(v.w);
    ((ushort4*)out)[i] = o;
  }
}

// =============== 256x256 phased GEMM for qkvg ===============
// X:[M=8192][K=1024], W:[N=4096][K=1024] bf16 row-major.
// 512 thr = 8 waves (2M x 4N), per-wave 128x64, BK=32, 4-deep LDS ring.
// Output: blocked layout (16x16 tiles, col-major within tile), silu for
// cols<3072, sigmoid for cols>=3072.
// Swizzle: phys colblock = logical cb ^ (row&3) ^ ((row>>2)&3); applied
// inversely on the global source of global_load_lds (both-sides rule).
__global__ __launch_bounds__(512) void gemm256_qkvg(
    const uint16_t* __restrict__ X, const uint16_t* __restrict__ W,
    uint16_t* __restrict__ Y)
{
  __shared__ __align__(16) uint16_t sA[4][8192];   // 4 bufs x 256 rows x 32 bf16
  __shared__ __align__(16) uint16_t sB[4][8192];
  constexpr int K = DD;
  constexpr int NT = K / 32;                        // 32 K-tiles

  const int tid = threadIdx.x;
  const int lin = blockIdx.x;
  const int swz = (lin & 7) * 64 + (lin >> 3);      // XCD swizzle (512%8==0)
  const int m0 = (swz >> 4) * 256, n0 = (swz & 15) * 256;
  const int l = tid & 63, w = tid >> 6;
  const int wr = w >> 2, wc = w & 3;
  const int g = l >> 4, r16 = l & 15;
  const int cb = g ^ (r16 & 3) ^ ((r16 >> 2) & 3);
  const int offA = (wr * 128 + r16) * 64 + cb * 16; // byte offsets in a buf
  const int offB = (wc * 64  + r16) * 64 + cb * 16;

  // staging: slot s (16B) holds logical (row=s>>2, cb = (s&3)^sw(row))
  const int s0r = tid >> 2,        s0c = ((tid & 3) ^ (s0r & 3) ^ ((s0r >> 2) & 3)) * 8;
  const int s1 = tid + 512;
  const int s1r = s1 >> 2,         s1c = ((s1 & 3) ^ (s1r & 3) ^ ((s1r >> 2) & 3)) * 8;
  const uint16_t* pA0 = X + (size_t)(m0 + s0r) * K + s0c;
  const uint16_t* pA1 = X + (size_t)(m0 + s1r) * K + s1c;
  const uint16_t* pB0 = W + (size_t)(n0 + s0r) * K + s0c;
  const uint16_t* pB1 = W + (size_t)(n0 + s1r) * K + s1c;
  const int dsl0 = w * 512, dsl1 = w * 512 + 4096;  // uint16 index (wave-uniform)

  // prologue: stage K-tiles 0 and 1
  gll16(pA0,      &sA[0][dsl0]); gll16(pA1,      &sA[0][dsl1]);
  gll16(pB0,      &sB[0][dsl0]); gll16(pB1,      &sB[0][dsl1]);
  gll16(pA0 + 32, &sA[1][dsl0]); gll16(pA1 + 32, &sA[1][dsl1]);
  gll16(pB0 + 32, &sB[1][dsl0]); gll16(pB1 + 32, &sB[1][dsl1]);
  pA0 += 64; pA1 += 64; pB0 += 64; pB1 += 64;

  f32x4 acc[8][4];
  #pragma unroll
  for (int i = 0; i < 8; i++)
    #pragma unroll
    for (int j = 0; j < 4; j++) acc[i][j] = (f32x4){0.f, 0.f, 0.f, 0.f};

  asm volatile("s_waitcnt vmcnt(4)" ::: "memory");  // tile0 resident
  __builtin_amdgcn_sched_barrier(0);
  block_barrier();

  #pragma unroll 4
  for (int t = 0; t < NT; ++t){
    const int buf = t & 3, buf2 = (t + 2) & 3;
    const bool stage = (t + 2 < NT);
    const char* bA = (const char*)&sA[buf][0];
    const char* bB = (const char*)&sB[buf][0];

    // ---- phase 0: A frags + B[0,1]; stage A(t+2) ----
    bf16x8 af[8], bf0[2];
    #pragma unroll
    for (int mi = 0; mi < 8; ++mi) af[mi] = *(const bf16x8*)(bA + offA + mi * 1024);
    bf0[0] = *(const bf16x8*)(bB + offB);
    bf0[1] = *(const bf16x8*)(bB + offB + 1024);
    if (stage){ gll16(pA0, &sA[buf2][dsl0]); gll16(pA1, &sA[buf2][dsl1]); }
    block_barrier();
    asm volatile("s_waitcnt lgkmcnt(0)" ::: "memory");
    __builtin_amdgcn_sched_barrier(0);
    __builtin_amdgcn_s_setprio(1);
    #pragma unroll
    for (int mi = 0; mi < 8; ++mi){
      acc[mi][0] = __builtin_amdgcn_mfma_f32_16x16x32_bf16(af[mi], bf0[0], acc[mi][0], 0, 0, 0);
      acc[mi][1] = __builtin_amdgcn_mfma_f32_16x16x32_bf16(af[mi], bf0[1], acc[mi][1], 0, 0, 0);
    }
    __builtin_amdgcn_s_setprio(0);
    block_barrier();

    // ---- phase 1: B[2,3]; stage B(t+2) ----
    bf16x8 bf1[2];
    bf1[0] = *(const bf16x8*)(bB + offB + 2048);
    bf1[1] = *(const bf16x8*)(bB + offB + 3072);
    if (stage){ gll16(pB0, &sB[buf2][dsl0]); gll16(pB1, &sB[buf2][dsl1]); }
    block_barrier();
    asm volatile("s_waitcnt lgkmcnt(0)" ::: "memory");
    __builtin_amdgcn_sched_barrier(0);
    __builtin_amdgcn_s_setprio(1);
    #pragma unroll
    for (int mi = 0; mi < 8; ++mi){
      acc[mi][2] = __builtin_amdgcn_mfma_f32_16x16x32_bf16(af[mi], bf1[0], acc[mi][2], 0, 0, 0);
      acc[mi][3] = __builtin_amdgcn_mfma_f32_16x16x32_bf16(af[mi], bf1[1], acc[mi][3], 0, 0, 0);
    }
    __builtin_amdgcn_s_setprio(0);
    pA0 += 32; pA1 += 32; pB0 += 32; pB1 += 32;
    if (t < NT - 2){
      asm volatile("s_waitcnt vmcnt(4)" ::: "memory");  // tile t+1 resident
      __builtin_amdgcn_sched_barrier(0);
    } else if (t == NT - 2){
      asm volatile("s_waitcnt vmcnt(0)" ::: "memory");  // final drain
      __builtin_amdgcn_sched_barrier(0);
    }
    if (t != NT - 1) block_barrier();
  }

  // epilogue: C/D col=lane&15, row=(lane>>4)*4+reg; blocked store, 8B/lane/frag
  const bool dosig = (n0 >= 3 * DD);
  #pragma unroll
  for (int mi = 0; mi < 8; ++mi){
    const int R0 = m0 + wr * 128 + mi * 16;           // R0 % 16 == 0
    const size_t rbase = (size_t)(R0 >> 4) * ROWT;
    #pragma unroll
    for (int ni = 0; ni < 4; ++ni){
      const int C = n0 + wc * 64 + ni * 16 + r16;
      f32x4 v = acc[mi][ni];
      float o[4];
      #pragma unroll
      for (int r = 0; r < 4; r++){
        float x = v[r];
        o[r] = dosig ? sigm(x) : x * sigm(x);
      }
      uint2 pk;
      pk.x = (uint32_t)f2bf(o[0]) | ((uint32_t)f2bf(o[1]) << 16);
      pk.y = (uint32_t)f2bf(o[2]) | ((uint32_t)f2bf(o[3]) << 16);
      size_t off = rbase + (size_t)(C >> 4) * 256 + (size_t)r16 * 16 + g * 4;
      *(uint2*)(Y + off) = pk;
    }
  }
}

// ---------------- old 128x128 GEMM (kept for Wo): Y = X @ W^T ----------------
template<int ACT, int BF16OUT>
__global__ __launch_bounds__(256) void gemm_bt(
    const uint16_t* __restrict__ X, const uint16_t* __restrict__ W,
    uint16_t* __restrict__ Yb, float* __restrict__ Yf, int M, int N, int K)
{
  __shared__ __align__(16) uint16_t lA[128*32];
  __shared__ __align__(16) uint16_t lB[128*32];
  const int tid = threadIdx.x;
  const int m0 = blockIdx.y * 128, n0 = blockIdx.x * 128;
  const int l = tid & 63, w = tid >> 6;
  const int wr = w >> 1, wc = w & 1;
  const int g = l >> 4, r16 = l & 15;
  const int p = (r16 >> 1) & 3;

  const int s0 = w * 128 + l, s1 = s0 + 64;
  const int r0 = s0 >> 2, c0 = (((s0 & 3) ^ ((r0 >> 1) & 3)) << 3);
  const int r1 = s1 >> 2, c1 = (((s1 & 3) ^ ((r1 >> 1) & 3)) << 3);
  const uint16_t* aS0 = X + (size_t)(m0 + r0) * K + c0;
  const uint16_t* aS1 = X + (size_t)(m0 + r1) * K + c1;
  const uint16_t* bS0 = W + (size_t)(n0 + r0) * K + c0;
  const uint16_t* bS1 = W + (size_t)(n0 + r1) * K + c1;
  uint16_t* dA0 = lA + w * 1024; uint16_t* dA1 = dA0 + 512;
  uint16_t* dB0 = lB + w * 1024; uint16_t* dB1 = dB0 + 512;

  int roA[4], roB[4];
  #pragma unroll
  for (int i = 0; i < 4; i++){
    roA[i] = (wr * 64 + i * 16 + r16) * 32 + ((g ^ p) << 3);
    roB[i] = (wc * 64 + i * 16 + r16) * 32 + ((g ^ p) << 3);
  }

  f32x4 acc[4][4];
  #pragma unroll
  for (int i = 0; i < 4; i++)
    #pragma unroll
    for (int j = 0; j < 4; j++) acc[i][j] = (f32x4){0.f, 0.f, 0.f, 0.f};

  for (int kt = 0; kt < K; kt += 32){
    __syncthreads();
    gll16(aS0 + kt, dA0); gll16(aS1 + kt, dA1);
    gll16(bS0 + kt, dB0); gll16(bS1 + kt, dB1);
    __syncthreads();

    bf16x8 af[4], bw[4];
    #pragma unroll
    for (int mi = 0; mi < 4; mi++) af[mi] = *(const bf16x8*)(lA + roA[mi]);
    #pragma unroll
    for (int ni = 0; ni < 4; ni++) bw[ni] = *(const bf16x8*)(lB + roB[ni]);

    #pragma unroll
    for (int mi = 0; mi < 4; mi++)
      #pragma unroll
      for (int ni = 0; ni < 4; ni++)
        acc[mi][ni] = __builtin_amdgcn_mfma_f32_16x16x32_bf16(af[mi], bw[ni], acc[mi][ni], 0, 0, 0);
  }

  #pragma unroll
  for (int mi = 0; mi < 4; mi++){
    #pragma unroll
    for (int ni = 0; ni < 4; ni++){
      int rg = m0 + wr * 64 + mi * 16 + g * 4;
      int cg = n0 + wc * 64 + ni * 16 + r16;
      #pragma unroll
      for (int r = 0; r < 4; r++){
        float v = acc[mi][ni][r];
        if (ACT == 1) v = v * sigm(v);
        else if (ACT == 2) v = sigm(v);
        if (BF16OUT) Yb[(size_t)(rg + r) * N + cg] = f2bf(v);
        else         Yf[(size_t)(rg + r) * N + cg] = v;
      }
    }
  }
}

// ---------------- small projections: sigmoid(x @ W^T + b), [3][B][H][T] ----------------
__global__ __launch_bounds__(256) void small_proj(
    const float* __restrict__ x,
    const float* __restrict__ Wb, const float* __restrict__ Wfd, const float* __restrict__ bfd,
    const float* __restrict__ Wsd, const float* __restrict__ bsd,
    float* __restrict__ sc)
{
  int token = blockIdx.x * 4 + (threadIdx.x >> 6);
  int lane = threadIdx.x & 63;
  const float4* xr = (const float4*)(x + (size_t)token * DD);
  float4 xv[4];
  #pragma unroll
  for (int i = 0; i < 4; i++) xv[i] = xr[lane * 4 + i];
  int b = token / TT, t = token % TT;

  for (int j = 0; j < 48; j++){
    int grp = j >> 4, h = j & 15;
    const float* wrow;
    float bias;
    if (grp == 0){ wrow = Wb  + (size_t)h * DD; bias = 0.f; }
    else if (grp == 1){ wrow = Wfd + (size_t)h * DD; bias = bfd[h]; }
    else { wrow = Wsd + (size_t)h * DD; bias = bsd[h]; }
    const float4* wr4 = (const float4*)wrow;
    float s = 0.f;
    #pragma unroll
    for (int i = 0; i < 4; i++){
      float4 wv = wr4[lane * 4 + i];
      s += xv[i].x * wv.x + xv[i].y * wv.y + xv[i].z * wv.z + xv[i].w * wv.w;
    }
    #pragma unroll
    for (int off = 32; off; off >>= 1) s += __shfl_xor(s, off);
    if (lane == 0) sc[(((size_t)grp * BB + b) * HH + h) * TT + t] = sigm(s + bias);
  }
}

// ---------------- chunked scan over blocked qkvg ----------------
// blocked elem(R,C) = (R>>4)*ROWT + (C>>4)*256 + (C&15)*16 + (R&15)
// step: [sf,ss]' = M_t [sf,ss] + 1.05*u_t*[1,1],  M_t = [[f,.05s],[.05f,s]]
// lane = channel c in [0,64); block = (chunk j, bh)

__global__ __launch_bounds__(64) void scan_partA(
    const uint16_t* __restrict__ qkvg, const float* __restrict__ sc,
    float* __restrict__ Lst, float4* __restrict__ Pm)
{
  int j = blockIdx.x, bh = blockIdx.y;
  int b = bh >> 4, h = bh & 15;
  int c = threadIdx.x;
  const int ci = c & 15;
  const size_t tc_k = (size_t)((DD     + h * 64 + c) >> 4) * 256 + ci * 16;
  const size_t tc_v = (size_t)((2 * DD + h * 64 + c) >> 4) * 256 + ci * 16;
  const float* bet = sc + ((size_t)(0 * BB + b) * HH + h) * TT + j * TC;
  const float* fdp = sc + ((size_t)(1 * BB + b) * HH + h) * TT + j * TC;
  const float* sdp = sc + ((size_t)(2 * BB + b) * HH + h) * TT + j * TC;

  float sf = 0.f, ss = 0.f;
  float p00 = 1.f, p01 = 0.f, p10 = 0.f, p11 = 1.f;
  #pragma unroll
  for (int t16 = 0; t16 < 2; ++t16){
    int R0 = b * TT + j * TC + t16 * 16;
    size_t tb = (size_t)(R0 >> 4) * ROWT;
    uint4 kl = *(const uint4*)(qkvg + tb + tc_k);
    uint4 kh = *(const uint4*)(qkvg + tb + tc_k + 8);
    uint4 vl = *(const uint4*)(qkvg + tb + tc_v);
    uint4 vh = *(const uint4*)(qkvg + tb + tc_v + 8);
    const float* bt = bet + t16 * 16;
    const float* ft = fdp + t16 * 16;
    const float* st = sdp + t16 * 16;
    #pragma unroll
    for (int u = 0; u < 16; ++u){
      float kv = (u < 8) ? bfel(kl, u) : bfel(kh, u - 8);
      float vv = (u < 8) ? bfel(vl, u) : bfel(vh, u - 8);
      float btv = bt[u], f = ft[u], s = st[u];
      float uu = 1.05f * btv * kv * vv;
      float bq = 0.05f * s, cq = 0.05f * f;
      float nf = f * sf + bq * ss + uu;
      float ns = cq * sf + s * ss + uu;
      sf = nf; ss = ns;
      float q00 = f * p00 + bq * p10, q01 = f * p01 + bq * p11;
      float q10 = cq * p00 + s * p10, q11 = cq * p01 + s * p11;
      p00 = q00; p01 = q01; p10 = q10; p11 = q11;
    }
  }
  size_t base = ((size_t)bh * NC + j) * 2;
  Lst[(base + 0) * 64 + c] = sf;
  Lst[(base + 1) * 64 + c] = ss;
  if (c == 0) Pm[(size_t)bh * NC + j] = make_float4(p00, p01, p10, p11);
}

__global__ __launch_bounds__(64) void scan_partB(
    const float* __restrict__ Lst, const float4* __restrict__ Pm, float* __restrict__ Est)
{
  int bh = blockIdx.x, dc = threadIdx.x;
  float xf = 0.f, xs = 0.f;
  for (int j = 0; j < NC; j++){
    size_t base = ((size_t)bh * NC + j) * 2;
    Est[(base + 0) * 64 + dc] = xf;
    Est[(base + 1) * 64 + dc] = xs;
    float4 P = Pm[(size_t)bh * NC + j];
    float lf = Lst[(base + 0) * 64 + dc], ls = Lst[(base + 1) * 64 + dc];
    float nf = P.x * xf + P.y * xs + lf;
    float ns = P.z * xf + P.w * xs + ls;
    xf = nf; xs = ns;
  }
}

__global__ __launch_bounds__(64) void scan_partC(
    const uint16_t* __restrict__ qkvg, const float* __restrict__ sc,
    const float* __restrict__ Est, uint16_t* __restrict__ og)
{
  int j = blockIdx.x, bh = blockIdx.y;
  int b = bh >> 4, h = bh & 15;
  int c = threadIdx.x;
  const int ci = c & 15;
  const size_t tc_q = (size_t)((         h * 64 + c) >> 4) * 256 + ci * 16;
  const size_t tc_k = (size_t)((DD     + h * 64 + c) >> 4) * 256 + ci * 16;
  const size_t tc_v = (size_t)((2 * DD + h * 64 + c) >> 4) * 256 + ci * 16;
  const size_t tc_g = (size_t)((3 * DD + h * 64 + c) >> 4) * 256 + ci * 16;
  const float* bet = sc + ((size_t)(0 * BB + b) * HH + h) * TT + j * TC;
  const float* fdp = sc + ((size_t)(1 * BB + b) * HH + h) * TT + j * TC;
  const float* sdp = sc + ((size_t)(2 * BB + b) * HH + h) * TT + j * TC;

  size_t base = ((size_t)bh * NC + j) * 2;
  float sf = Est[(base + 0) * 64 + c];
  float ss = Est[(base + 1) * 64 + c];

  #pragma unroll
  for (int t16 = 0; t16 < 2; ++t16){
    int R0 = b * TT + j * TC + t16 * 16;
    size_t tb = (size_t)(R0 >> 4) * ROWT;
    uint4 ql = *(const uint4*)(qkvg + tb + tc_q);
    uint4 qh = *(const uint4*)(qkvg + tb + tc_q + 8);
    uint4 kl = *(const uint4*)(qkvg + tb + tc_k);
    uint4 kh = *(const uint4*)(qkvg + tb + tc_k + 8);
    uint4 vl = *(const uint4*)(qkvg + tb + tc_v);
    uint4 vh = *(const uint4*)(qkvg + tb + tc_v + 8);
    uint4 gl = *(const uint4*)(qkvg + tb + tc_g);
    uint4 gh = *(const uint4*)(qkvg + tb + tc_g + 8);
    const float* bt = bet + t16 * 16;
    const float* ft = fdp + t16 * 16;
    const float* st = sdp + t16 * 16;
    uint16_t* op = og + (size_t)R0 * DD + h * 64 + c;
    #pragma unroll
    for (int u = 0; u < 16; ++u){
      float qv = (u < 8) ? bfel(ql, u) : bfel(qh, u - 8);
      float kv = (u < 8) ? bfel(kl, u) : bfel(kh, u - 8);
      float vv = (u < 8) ? bfel(vl, u) : bfel(vh, u - 8);
      float gv = (u < 8) ? bfel(gl, u) : bfel(gh, u - 8);
      float btv = bt[u], f = ft[u], s = st[u];
      sf *= f; ss *= s;
      float o = 0.5f * qv * (sf + ss);
      float uu = btv * kv * vv;
      sf += uu; ss += uu;
      float nf = sf + 0.05f * ss, ns = ss + 0.05f * sf;
      sf = nf; ss = ns;
      op[(size_t)u * DD] = f2bf(o * gv);
    }
  }
}

extern "C" void kernel_launch(void* const* d_in, const int* in_sizes, int n_in,
                              void* d_out, int out_size, void* d_ws, size_t ws_size,
                              hipStream_t stream)
{
  const float* x   = (const float*)d_in[0];
  const float* Wq  = (const float*)d_in[1];
  const float* Wk  = (const float*)d_in[2];
  const float* Wv  = (const float*)d_in[3];
  const float* Wo  = (const float*)d_in[4];
  const float* Wb  = (const float*)d_in[5];
  const float* Wfd = (const float*)d_in[6];
  const float* bfd = (const float*)d_in[7];
  const float* Wsd = (const float*)d_in[8];
  const float* bsd = (const float*)d_in[9];
  const float* Wg  = (const float*)d_in[10];
  float* out = (float*)d_out;

  char* ws = (char*)d_ws;
  size_t off = 0;
  auto alloc = [&](size_t bytes) -> void* {
    void* p = ws + off;
    off += (bytes + 255) & ~(size_t)255;
    return p;
  };

  uint16_t* xb   = (uint16_t*)alloc((size_t)MTOK * DD * 2);   // doubles as ogb later
  uint16_t* wcat = (uint16_t*)alloc((size_t)4 * DD * DD * 2); // Wq|Wk|Wv|Wg
  uint16_t* wob  = (uint16_t*)alloc((size_t)DD * DD * 2);
  uint16_t* qkvg = (uint16_t*)alloc((size_t)MTOK * NQ * 2);   // blocked layout
  float*    sc   = (float*)alloc((size_t)3 * BB * HH * TT * 4);
  float*    Lst  = (float*)alloc((size_t)BH * NC * 2 * 64 * 4);
  float*    Est  = (float*)alloc((size_t)BH * NC * 2 * 64 * 4);
  float4*   Pm   = (float4*)alloc((size_t)BH * NC * 16);
  uint16_t* ogb  = xb;

  int n4x = MTOK * DD / 4;
  cvt_kernel<<<(n4x + 255) / 256, 256, 0, stream>>>(x, xb, n4x);
  int n4w = DD * DD / 4;
  cvt_kernel<<<(n4w + 255) / 256, 256, 0, stream>>>(Wq, wcat + 0 * DD * DD, n4w);
  cvt_kernel<<<(n4w + 255) / 256, 256, 0, stream>>>(Wk, wcat + 1 * DD * DD, n4w);
  cvt_kernel<<<(n4w + 255) / 256, 256, 0, stream>>>(Wv, wcat + 2 * DD * DD, n4w);
  cvt_kernel<<<(n4w + 255) / 256, 256, 0, stream>>>(Wg, wcat + 3 * DD * DD, n4w);
  cvt_kernel<<<(n4w + 255) / 256, 256, 0, stream>>>(Wo, wob, n4w);

  small_proj<<<MTOK / 4, 256, 0, stream>>>(x, Wb, Wfd, bfd, Wsd, bsd, sc);

  // fused q|k|v|g GEMM: [8192,1024] @ [4096,1024]^T -> blocked bf16
  gemm256_qkvg<<<(MTOK / 256) * (NQ / 256), 512, 0, stream>>>(xb, wcat, qkvg);

  // chunked scan
  dim3 gs(NC, BH);
  scan_partA<<<gs, 64, 0, stream>>>(qkvg, sc, Lst, Pm);
  scan_partB<<<BH, 64, 0, stream>>>(Lst, Pm, Est);
  scan_partC<<<gs, 64, 0, stream>>>(qkvg, sc, Est, ogb);

  // out = (o*g) @ Wo^T, fp32 out
  dim3 go(DD / 128, MTOK / 128);
  gemm_bt<0, 0><<<go, 256, 0, stream>>>(ogb, wob, nullptr, out, MTOK, DD, DD);
}

// Round 4
// 218.836 us; speedup vs baseline: 1.2789x; 1.2789x over previous
//
#include <hip/hip_runtime.h>
#include <hip/hip_bf16.h>
#include <stdint.h>

#define BB 4
#define TT 2048
#define DD 1024
#define HH 16
#define MTOK (BB*TT)
#define NQ 4096            // q|k|v|g concat width
#define TC 32              // scan chunk length
#define NC (TT/TC)         // 64 chunks
#define BH (BB*HH)         // 64
#define ROWT (16*NQ)       // elements per 16-row blocked stripe

typedef __bf16 bf16x8 __attribute__((ext_vector_type(8)));
typedef float f32x4 __attribute__((ext_vector_type(4)));

__device__ __forceinline__ uint16_t f2bf(float f){
  uint32_t u = __float_as_uint(f);
  u += 0x7fffu + ((u >> 16) & 1u);
  return (uint16_t)(u >> 16);
}
__device__ __forceinline__ float bf2f(uint32_t h){ return __uint_as_float(h << 16); }
__device__ __forceinline__ float sigm(float z){ return 1.f / (1.f + __expf(-z)); }

__device__ __forceinline__ void gll16(const uint16_t* src, uint16_t* dst){
  __builtin_amdgcn_global_load_lds(
      (const __attribute__((address_space(1))) void*)src,
      (__attribute__((address_space(3))) void*)dst, 16, 0, 0);
}
// extract bf16 element e (static) from a uint4 (8 bf16)
__device__ __forceinline__ float bfel(const uint4& v, int e){
  uint32_t wrd = ((e>>1)==0) ? v.x : ((e>>1)==1) ? v.y : ((e>>1)==2) ? v.z : v.w;
  return bf2f((e&1) ? (wrd >> 16) : (wrd & 0xffffu));
}

// ---------------- fused weight f32 -> bf16 cast (Wq|Wk|Wv|Wg -> wcat, Wo -> wob) ----------------
__global__ __launch_bounds__(256) void wcvt_kernel(
    const float* __restrict__ w0, const float* __restrict__ w1,
    const float* __restrict__ w2, const float* __restrict__ w3,
    const float* __restrict__ w4, uint16_t* __restrict__ wcat, uint16_t* __restrict__ wob)
{
  int i = blockIdx.x * 256 + threadIdx.x;      // float4 index; 262144 per weight
  int wsel = i >> 18;
  int loc = i & 262143;
  const float* src = (wsel == 0) ? w0 : (wsel == 1) ? w1 : (wsel == 2) ? w2 : (wsel == 3) ? w3 : w4;
  uint16_t* dst = (wsel < 4) ? (wcat + (size_t)wsel * DD * DD) : wob;
  float4 v = ((const float4*)src)[loc];
  ushort4 o;
  o.x = f2bf(v.x); o.y = f2bf(v.y); o.z = f2bf(v.z); o.w = f2bf(v.w);
  ((ushort4*)dst)[loc] = o;
}

// =============== 128x128 GEMM, BK=64, m97 2-barrier structure ===============
// X:[M][K], W:[N][K] bf16 row-major (K-contiguous). 256 thr = 4 waves (2x2),
// 64x64 per wave. LDS 2x16KB. Per-8-row XOR swizzle on the 16B quarter index:
// LDS chunk p (16B) holds logical (row=p>>3, quarter=(p&7)^(row&7)); applied
// inversely on the global source of global_load_lds (rule #21).
// MODE 0: qkvg (blocked bf16 out into Y, N=NQ; silu cols<3072 else sigmoid)
// MODE 1: plain f32 row-major out into Yf, no activation
template<int MODE>
__global__ __launch_bounds__(256) void gemm128(
    const uint16_t* __restrict__ X, const uint16_t* __restrict__ W,
    uint16_t* __restrict__ Y, float* __restrict__ Yf, int N, int K)
{
  __shared__ __align__(16) uint16_t lA[128 * 64];
  __shared__ __align__(16) uint16_t lB[128 * 64];
  const int tid = threadIdx.x;
  const int m0 = blockIdx.y * 128, n0 = blockIdx.x * 128;
  const int l = tid & 63, w = tid >> 6;
  const int wr = w >> 1, wc = w & 1;
  const int g = l >> 4, r16 = l & 15;

  // staging: chunk p = n*256 + tid; row = p>>3, logical quarter = (p&7)^(row&7)
  const uint16_t* srcA[4];
  const uint16_t* srcB[4];
  uint16_t* dstA[4];
  uint16_t* dstB[4];
  #pragma unroll
  for (int n = 0; n < 4; n++){
    int p = n * 256 + tid;
    int row = p >> 3;
    int cq = (p & 7) ^ (row & 7);
    srcA[n] = X + (size_t)(m0 + row) * K + cq * 8;
    srcB[n] = W + (size_t)(n0 + row) * K + cq * 8;
    int basechunk = n * 256 + (tid & ~63);     // wave-uniform
    dstA[n] = lA + basechunk * 8;
    dstB[n] = lB + basechunk * 8;
  }

  // frag read offsets (uint16 idx): row*64 + ((ks*4+g)^(row&7))*8, row%8 == r16%8
  int roA[4][2], roB[4][2];
  #pragma unroll
  for (int i = 0; i < 4; i++)
    #pragma unroll
    for (int ks = 0; ks < 2; ks++){
      roA[i][ks] = (wr * 64 + i * 16 + r16) * 64 + ((ks * 4 + g) ^ (r16 & 7)) * 8;
      roB[i][ks] = (wc * 64 + i * 16 + r16) * 64 + ((ks * 4 + g) ^ (r16 & 7)) * 8;
    }

  f32x4 acc[4][4];
  #pragma unroll
  for (int i = 0; i < 4; i++)
    #pragma unroll
    for (int j = 0; j < 4; j++) acc[i][j] = (f32x4){0.f, 0.f, 0.f, 0.f};

  for (int kt = 0; kt < K; kt += 64){
    __syncthreads();                    // WAR: prior tile reads done
    #pragma unroll
    for (int n = 0; n < 4; n++){
      gll16(srcA[n] + kt, dstA[n]);
      gll16(srcB[n] + kt, dstB[n]);
    }
    __syncthreads();                    // compiler drains vmcnt(0) before barrier

    #pragma unroll
    for (int ks = 0; ks < 2; ks++){
      bf16x8 af[4], bw[4];
      #pragma unroll
      for (int mi = 0; mi < 4; mi++) af[mi] = *(const bf16x8*)(lA + roA[mi][ks]);
      #pragma unroll
      for (int ni = 0; ni < 4; ni++) bw[ni] = *(const bf16x8*)(lB + roB[ni][ks]);
      #pragma unroll
      for (int mi = 0; mi < 4; mi++)
        #pragma unroll
        for (int ni = 0; ni < 4; ni++)
          acc[mi][ni] = __builtin_amdgcn_mfma_f32_16x16x32_bf16(af[mi], bw[ni], acc[mi][ni], 0, 0, 0);
    }
  }

  // C/D layout: col=lane&15, row=(lane>>4)*4+reg  [m89-verified]
  if (MODE == 0){
    const bool dosig = (n0 >= 3 * DD);
    #pragma unroll
    for (int mi = 0; mi < 4; mi++){
      const int R0 = m0 + wr * 64 + mi * 16;
      const size_t rbase = (size_t)(R0 >> 4) * ROWT;
      #pragma unroll
      for (int ni = 0; ni < 4; ni++){
        const int C0 = n0 + wc * 64 + ni * 16;
        f32x4 v = acc[mi][ni];
        float o[4];
        #pragma unroll
        for (int r = 0; r < 4; r++){
          float xx = v[r];
          o[r] = dosig ? sigm(xx) : xx * sigm(xx);
        }
        uint2 pk;
        pk.x = (uint32_t)f2bf(o[0]) | ((uint32_t)f2bf(o[1]) << 16);
        pk.y = (uint32_t)f2bf(o[2]) | ((uint32_t)f2bf(o[3]) << 16);
        size_t off = rbase + (size_t)(C0 >> 4) * 256 + (size_t)r16 * 16 + g * 4;
        *(uint2*)(Y + off) = pk;
      }
    }
  } else {
    #pragma unroll
    for (int mi = 0; mi < 4; mi++){
      #pragma unroll
      for (int ni = 0; ni < 4; ni++){
        int rg = m0 + wr * 64 + mi * 16 + g * 4;
        int cg = n0 + wc * 64 + ni * 16 + r16;
        #pragma unroll
        for (int r = 0; r < 4; r++)
          Yf[(size_t)(rg + r) * N + cg] = acc[mi][ni][r];
      }
    }
  }
}

// ---------------- small projections fused with x->bf16 cast ----------------
// block = 256 thr = 4 waves; wave handles 4 tokens (16/block).
// sc layout [3][B][H][T]; also writes xb (bf16 row-major).
__global__ __launch_bounds__(256) void small_proj_cast(
    const float* __restrict__ x,
    const float* __restrict__ Wb, const float* __restrict__ Wfd, const float* __restrict__ bfd,
    const float* __restrict__ Wsd, const float* __restrict__ bsd,
    float* __restrict__ sc, uint16_t* __restrict__ xb)
{
  int w = threadIdx.x >> 6, lane = threadIdx.x & 63;
  int tok0 = blockIdx.x * 16 + w * 4;

  float4 xv[4][4];
  #pragma unroll
  for (int tk = 0; tk < 4; tk++){
    const float4* xr = (const float4*)(x + (size_t)(tok0 + tk) * DD);
    #pragma unroll
    for (int i = 0; i < 4; i++) xv[tk][i] = xr[lane * 4 + i];
    // cast store: 16 bf16 = 2 x uint4
    uint4 o0, o1;
    o0.x = (uint32_t)f2bf(xv[tk][0].x) | ((uint32_t)f2bf(xv[tk][0].y) << 16);
    o0.y = (uint32_t)f2bf(xv[tk][0].z) | ((uint32_t)f2bf(xv[tk][0].w) << 16);
    o0.z = (uint32_t)f2bf(xv[tk][1].x) | ((uint32_t)f2bf(xv[tk][1].y) << 16);
    o0.w = (uint32_t)f2bf(xv[tk][1].z) | ((uint32_t)f2bf(xv[tk][1].w) << 16);
    o1.x = (uint32_t)f2bf(xv[tk][2].x) | ((uint32_t)f2bf(xv[tk][2].y) << 16);
    o1.y = (uint32_t)f2bf(xv[tk][2].z) | ((uint32_t)f2bf(xv[tk][2].w) << 16);
    o1.z = (uint32_t)f2bf(xv[tk][3].x) | ((uint32_t)f2bf(xv[tk][3].y) << 16);
    o1.w = (uint32_t)f2bf(xv[tk][3].z) | ((uint32_t)f2bf(xv[tk][3].w) << 16);
    uint4* xo = (uint4*)(xb + (size_t)(tok0 + tk) * DD + lane * 16);
    xo[0] = o0; xo[1] = o1;
  }

  for (int j = 0; j < 48; j++){
    int grp = j >> 4, h = j & 15;
    const float* wrow;
    float bias;
    if (grp == 0){ wrow = Wb  + (size_t)h * DD; bias = 0.f; }
    else if (grp == 1){ wrow = Wfd + (size_t)h * DD; bias = bfd[h]; }
    else { wrow = Wsd + (size_t)h * DD; bias = bsd[h]; }
    const float4* wr4 = (const float4*)wrow;
    float4 wv[4];
    #pragma unroll
    for (int i = 0; i < 4; i++) wv[i] = wr4[lane * 4 + i];
    #pragma unroll
    for (int tk = 0; tk < 4; tk++){
      float s = 0.f;
      #pragma unroll
      for (int i = 0; i < 4; i++)
        s += xv[tk][i].x * wv[i].x + xv[tk][i].y * wv[i].y + xv[tk][i].z * wv[i].z + xv[tk][i].w * wv[i].w;
      #pragma unroll
      for (int off = 32; off; off >>= 1) s += __shfl_xor(s, off);
      if (lane == 0){
        int token = tok0 + tk;
        int b = token / TT, t = token % TT;
        sc[(((size_t)grp * BB + b) * HH + h) * TT + t] = sigm(s + bias);
      }
    }
  }
}

// ---------------- chunked scan over blocked qkvg ----------------
// blocked elem(R,C) = (R>>4)*ROWT + (C>>4)*256 + (C&15)*16 + (R&15)
// step: [sf,ss]' = M_t [sf,ss] + 1.05*u_t*[1,1],  M_t = [[f,.05s],[.05f,s]]

__global__ __launch_bounds__(64) void scan_partA(
    const uint16_t* __restrict__ qkvg, const float* __restrict__ sc,
    float* __restrict__ Lst, float4* __restrict__ Pm)
{
  int j = blockIdx.x, bh = blockIdx.y;
  int b = bh >> 4, h = bh & 15;
  int c = threadIdx.x;
  const int ci = c & 15;
  const size_t tc_k = (size_t)((DD     + h * 64 + c) >> 4) * 256 + ci * 16;
  const size_t tc_v = (size_t)((2 * DD + h * 64 + c) >> 4) * 256 + ci * 16;
  const float* bet = sc + ((size_t)(0 * BB + b) * HH + h) * TT + j * TC;
  const float* fdp = sc + ((size_t)(1 * BB + b) * HH + h) * TT + j * TC;
  const float* sdp = sc + ((size_t)(2 * BB + b) * HH + h) * TT + j * TC;

  float sf = 0.f, ss = 0.f;
  float p00 = 1.f, p01 = 0.f, p10 = 0.f, p11 = 1.f;
  #pragma unroll
  for (int t16 = 0; t16 < 2; ++t16){
    int R0 = b * TT + j * TC + t16 * 16;
    size_t tb = (size_t)(R0 >> 4) * ROWT;
    uint4 kl = *(const uint4*)(qkvg + tb + tc_k);
    uint4 kh = *(const uint4*)(qkvg + tb + tc_k + 8);
    uint4 vl = *(const uint4*)(qkvg + tb + tc_v);
    uint4 vh = *(const uint4*)(qkvg + tb + tc_v + 8);
    const float* bt = bet + t16 * 16;
    const float* ft = fdp + t16 * 16;
    const float* st = sdp + t16 * 16;
    #pragma unroll
    for (int u = 0; u < 16; ++u){
      float kv = (u < 8) ? bfel(kl, u) : bfel(kh, u - 8);
      float vv = (u < 8) ? bfel(vl, u) : bfel(vh, u - 8);
      float btv = bt[u], f = ft[u], s = st[u];
      float uu = 1.05f * btv * kv * vv;
      float bq = 0.05f * s, cq = 0.05f * f;
      float nf = f * sf + bq * ss + uu;
      float ns = cq * sf + s * ss + uu;
      sf = nf; ss = ns;
      float q00 = f * p00 + bq * p10, q01 = f * p01 + bq * p11;
      float q10 = cq * p00 + s * p10, q11 = cq * p01 + s * p11;
      p00 = q00; p01 = q01; p10 = q10; p11 = q11;
    }
  }
  size_t base = ((size_t)bh * NC + j) * 2;
  Lst[(base + 0) * 64 + c] = sf;
  Lst[(base + 1) * 64 + c] = ss;
  if (c == 0) Pm[(size_t)bh * NC + j] = make_float4(p00, p01, p10, p11);
}

__global__ __launch_bounds__(64) void scan_partB(
    const float* __restrict__ Lst, const float4* __restrict__ Pm, float* __restrict__ Est)
{
  int bh = blockIdx.x, dc = threadIdx.x;
  float xf = 0.f, xs = 0.f;
  for (int j = 0; j < NC; j++){
    size_t base = ((size_t)bh * NC + j) * 2;
    Est[(base + 0) * 64 + dc] = xf;
    Est[(base + 1) * 64 + dc] = xs;
    float4 P = Pm[(size_t)bh * NC + j];
    float lf = Lst[(base + 0) * 64 + dc], ls = Lst[(base + 1) * 64 + dc];
    float nf = P.x * xf + P.y * xs + lf;
    float ns = P.z * xf + P.w * xs + ls;
    xf = nf; xs = ns;
  }
}

// Pass C: replay chunk; write og = o*g ROW-MAJOR via LDS micro-transpose.
__global__ __launch_bounds__(64) void scan_partC(
    const uint16_t* __restrict__ qkvg, const float* __restrict__ sc,
    const float* __restrict__ Est, uint16_t* __restrict__ og)
{
  __shared__ uint16_t ot[16 * 64];                 // [u][c]
  int j = blockIdx.x, bh = blockIdx.y;
  int b = bh >> 4, h = bh & 15;
  int c = threadIdx.x;
  const int ci = c & 15;
  const size_t tc_q = (size_t)((         h * 64 + c) >> 4) * 256 + ci * 16;
  const size_t tc_k = (size_t)((DD     + h * 64 + c) >> 4) * 256 + ci * 16;
  const size_t tc_v = (size_t)((2 * DD + h * 64 + c) >> 4) * 256 + ci * 16;
  const size_t tc_g = (size_t)((3 * DD + h * 64 + c) >> 4) * 256 + ci * 16;
  const float* bet = sc + ((size_t)(0 * BB + b) * HH + h) * TT + j * TC;
  const float* fdp = sc + ((size_t)(1 * BB + b) * HH + h) * TT + j * TC;
  const float* sdp = sc + ((size_t)(2 * BB + b) * HH + h) * TT + j * TC;

  size_t base = ((size_t)bh * NC + j) * 2;
  float sf = Est[(base + 0) * 64 + c];
  float ss = Est[(base + 1) * 64 + c];

  #pragma unroll
  for (int t16 = 0; t16 < 2; ++t16){
    int R0 = b * TT + j * TC + t16 * 16;
    size_t tb = (size_t)(R0 >> 4) * ROWT;
    uint4 ql = *(const uint4*)(qkvg + tb + tc_q);
    uint4 qh = *(const uint4*)(qkvg + tb + tc_q + 8);
    uint4 kl = *(const uint4*)(qkvg + tb + tc_k);
    uint4 kh = *(const uint4*)(qkvg + tb + tc_k + 8);
    uint4 vl = *(const uint4*)(qkvg + tb + tc_v);
    uint4 vh = *(const uint4*)(qkvg + tb + tc_v + 8);
    uint4 gl = *(const uint4*)(qkvg + tb + tc_g);
    uint4 gh = *(const uint4*)(qkvg + tb + tc_g + 8);
    const float* bt = bet + t16 * 16;
    const float* ft = fdp + t16 * 16;
    const float* st = sdp + t16 * 16;
    #pragma unroll
    for (int u = 0; u < 16; ++u){
      float qv = (u < 8) ? bfel(ql, u) : bfel(qh, u - 8);
      float kv = (u < 8) ? bfel(kl, u) : bfel(kh, u - 8);
      float vv = (u < 8) ? bfel(vl, u) : bfel(vh, u - 8);
      float gv = (u < 8) ? bfel(gl, u) : bfel(gh, u - 8);
      float btv = bt[u], f = ft[u], s = st[u];
      sf *= f; ss *= s;
      float o = 0.5f * qv * (sf + ss);
      float uu = btv * kv * vv;
      sf += uu; ss += uu;
      float nf = sf + 0.05f * ss, ns = ss + 0.05f * sf;
      sf = nf; ss = ns;
      ot[u * 64 + c] = f2bf(o * gv);               // bank c>>1: 2-way, free
    }
    __syncthreads();
    {
      int u0 = c >> 3, c8 = c & 7;                 // chunk l: (u0, c8); chunk l+64: (u0+8, c8)
      uint4 d0 = *(const uint4*)&ot[u0 * 64 + c8 * 8];
      uint4 d1 = *(const uint4*)&ot[(u0 + 8) * 64 + c8 * 8];
      uint16_t* ob = og + (size_t)R0 * DD + h * 64 + c8 * 8;
      *(uint4*)(ob + (size_t)u0 * DD) = d0;
      *(uint4*)(ob + (size_t)(u0 + 8) * DD) = d1;
    }
    __syncthreads();
  }
}

extern "C" void kernel_launch(void* const* d_in, const int* in_sizes, int n_in,
                              void* d_out, int out_size, void* d_ws, size_t ws_size,
                              hipStream_t stream)
{
  const float* x   = (const float*)d_in[0];
  const float* Wq  = (const float*)d_in[1];
  const float* Wk  = (const float*)d_in[2];
  const float* Wv  = (const float*)d_in[3];
  const float* Wo  = (const float*)d_in[4];
  const float* Wb  = (const float*)d_in[5];
  const float* Wfd = (const float*)d_in[6];
  const float* bfd = (const float*)d_in[7];
  const float* Wsd = (const float*)d_in[8];
  const float* bsd = (const float*)d_in[9];
  const float* Wg  = (const float*)d_in[10];
  float* out = (float*)d_out;

  char* ws = (char*)d_ws;
  size_t off = 0;
  auto alloc = [&](size_t bytes) -> void* {
    void* p = ws + off;
    off += (bytes + 255) & ~(size_t)255;
    return p;
  };

  uint16_t* xb   = (uint16_t*)alloc((size_t)MTOK * DD * 2);   // doubles as ogb later
  uint16_t* wcat = (uint16_t*)alloc((size_t)4 * DD * DD * 2); // Wq|Wk|Wv|Wg
  uint16_t* wob  = (uint16_t*)alloc((size_t)DD * DD * 2);
  uint16_t* qkvg = (uint16_t*)alloc((size_t)MTOK * NQ * 2);   // blocked layout
  float*    sc   = (float*)alloc((size_t)3 * BB * HH * TT * 4);
  float*    Lst  = (float*)alloc((size_t)BH * NC * 2 * 64 * 4);
  float*    Est  = (float*)alloc((size_t)BH * NC * 2 * 64 * 4);
  float4*   Pm   = (float4*)alloc((size_t)BH * NC * 16);
  uint16_t* ogb  = xb;

  // weights cast (one kernel): 5 x 262144 float4
  wcvt_kernel<<<5 * 1024, 256, 0, stream>>>(Wq, Wk, Wv, Wg, Wo, wcat, wob);

  // small projections + x cast
  small_proj_cast<<<MTOK / 16, 256, 0, stream>>>(x, Wb, Wfd, bfd, Wsd, bsd, sc, xb);

  // fused q|k|v|g GEMM: [8192,1024] @ [4096,1024]^T -> blocked bf16
  dim3 gq(NQ / 128, MTOK / 128);
  gemm128<0><<<gq, 256, 0, stream>>>(xb, wcat, qkvg, nullptr, NQ, DD);

  // chunked scan
  dim3 gs(NC, BH);
  scan_partA<<<gs, 64, 0, stream>>>(qkvg, sc, Lst, Pm);
  scan_partB<<<BH, 64, 0, stream>>>(Lst, Pm, Est);
  scan_partC<<<gs, 64, 0, stream>>>(qkvg, sc, Est, ogb);

  // out = (o*g) @ Wo^T, fp32 row-major out
  dim3 go(DD / 128, MTOK / 128);
  gemm128<1><<<go, 256, 0, stream>>>(ogb, wob, nullptr, out, DD, DD);
}